// Round 3
// baseline (99.652 us; speedup 1.0000x reference)
//
#include <hip/hip_runtime.h>
#include <math.h>

#define N_ 2048
#define K_ 512
#define J_ 256
#define BN 64          // n per block (= lanes per wave)
#define BJ 32          // j per block; 8 per wave
#define K4 (K_ / 4)    // 128 float4 k-steps, full K staged once

// One block = 64n x 32j output tile, 256 threads (4 waves).
// lane <-> n (64 rows); each wave owns 8 consecutive j (wave-uniform -> w via s_load).
// x staged once: LDS [k4][n ^ (k4&63)] float4, 128 KB, XOR swizzle makes both the
// transpose-write (lanes sweep k4) and the read (lanes sweep n) conflict-free.
__global__ __launch_bounds__(256) void mam_fused(
    const float* __restrict__ x, const float* __restrict__ w,
    const float* __restrict__ bias, float* __restrict__ out)
{
    __shared__ __align__(16) float4 xs[K4 * BN];   // 128 KB

    const int t    = threadIdx.x;
    const int lane = t & 63;
    const int widx = __builtin_amdgcn_readfirstlane(t >> 6);   // scalar wave id
    const int n0    = blockIdx.x * BN;                 // x = n-block: j-siblings (y) are
    const int jbase = blockIdx.y * BJ + widx * 8;      // ids +32 apart -> same XCD -> x L2 hits

    float mx[8], mn[8];
#pragma unroll
    for (int j = 0; j < 8; ++j) { mx[j] = -__builtin_inff(); mn[j] = __builtin_inff(); }

    // ---- stage all of x[n0..n0+63][0..511] : 8192 float4, 32 per thread ----
#pragma unroll
    for (int r = 0; r < 32; ++r) {
        const int idx = r * 256 + t;        // float4 index
        const int nn  = idx >> 7;           // 128 float4 per row
        const int k4  = idx & (K4 - 1);
        const float4 g = *(const float4*)(x + (size_t)(n0 + nn) * K_ + k4 * 4);
        xs[k4 * BN + (nn ^ (k4 & 63))] = g;
    }
    __syncthreads();   // the only barrier

    // ---- main loop: w via scalar loads (wave-uniform), x via ds_read_b128 ----
    const float* wc = w + (size_t)jbase * K_;          // scalar base
#pragma unroll 2
    for (int k4 = 0; k4 < K4; ++k4) {
        const float4 xv = xs[k4 * BN + (lane ^ (k4 & 63))];
#pragma unroll
        for (int jj = 0; jj < 8; ++jj) {
            const float4 wv = *(const float4*)(wc + jj * K_ + k4 * 4);  // s_load_dwordx4
            const float p0 = xv.x * wv.x;
            const float p1 = xv.y * wv.y;
            const float p2 = xv.z * wv.z;
            const float p3 = xv.w * wv.w;
            // fmax(fmax(a,b),c) -> v_max3_f32 : 1 inst per 2 products
            mx[jj] = fmaxf(fmaxf(mx[jj], p0), p1);
            mn[jj] = fminf(fminf(mn[jj], p0), p1);
            mx[jj] = fmaxf(fmaxf(mx[jj], p2), p3);
            mn[jj] = fminf(fminf(mn[jj], p2), p3);
        }
    }

    // ---- epilogue: 8 consecutive j per lane, two dwordx4 stores ----
    const float* bb = bias + jbase;                    // uniform -> s_load
    float o[8];
#pragma unroll
    for (int jj = 0; jj < 8; ++jj) o[jj] = mx[jj] + mn[jj] + bb[jj];
    float* op = out + (size_t)(n0 + lane) * J_ + jbase;
    *(float4*)(op)     = make_float4(o[0], o[1], o[2], o[3]);
    *(float4*)(op + 4) = make_float4(o[4], o[5], o[6], o[7]);
}

extern "C" void kernel_launch(void* const* d_in, const int* in_sizes, int n_in,
                              void* d_out, int out_size, void* d_ws, size_t ws_size,
                              hipStream_t stream) {
    const float* x    = (const float*)d_in[0];
    const float* w    = (const float*)d_in[1];
    const float* bias = (const float*)d_in[2];
    float* out = (float*)d_out;

    dim3 grid(N_ / BN, J_ / BJ);   // (32 n-blocks, 8 j-blocks) = 256 blocks, 1/CU
    mam_fused<<<grid, 256, 0, stream>>>(x, w, bias, out);
}

// Round 4
// 99.226 us; speedup vs baseline: 1.0043x; 1.0043x over previous
//
#include <hip/hip_runtime.h>
#include <math.h>

#define N_ 2048
#define K_ 512
#define J_ 256
#define BKC 128            // staged k per chunk (32 float4), 32 KB LDS

typedef __attribute__((ext_vector_type(2))) float v2f;

// Block: 64n (lane) x 16j (4 waves x 4j, wave-uniform -> w via s_load), K-range = 512/ksplit.
// x staged per 128-k chunk in LDS [k4][lane^k4] (XOR swizzle, conflict-free both ways).
// 1024 blocks at ksplit=2 -> 4 blocks/CU -> 16 waves/CU -> 4/SIMD for latency hiding.
__global__ __launch_bounds__(256) void mam_main(
    const float* __restrict__ x, const float* __restrict__ w,
    const float* __restrict__ bias, float* __restrict__ out,
    float* __restrict__ pmax, float* __restrict__ pmin, int ksplit)
{
    __shared__ __align__(16) float4 xs[32 * 64];   // 32 KB

    const int t    = threadIdx.x;
    const int lane = t & 63;
    const int wid  = __builtin_amdgcn_readfirstlane(t >> 6);
    const int n0   = blockIdx.x * 64;
    const int j0   = blockIdx.y * 16 + wid * 4;    // wave-uniform
    const int kRange = K_ / ksplit;
    const int k0   = blockIdx.z * kRange;

    float mx[4], mn[4];
#pragma unroll
    for (int jj = 0; jj < 4; ++jj) { mx[jj] = -__builtin_inff(); mn[jj] = __builtin_inff(); }

    const float* wr = w + (size_t)j0 * K_;         // uniform -> scalar loads

    for (int kc = k0; kc < k0 + kRange; kc += BKC) {
        // ---- stage x[n0..n0+63][kc..kc+127] : 2048 float4, 8 per thread ----
        float4 g[8];
#pragma unroll
        for (int r = 0; r < 8; ++r) {
            const int idx = r * 256 + t;
            const int nn  = idx >> 5;              // 32 float4 per row
            const int kk4 = idx & 31;
            g[r] = *(const float4*)(x + (size_t)(n0 + nn) * K_ + kc + kk4 * 4);
        }
        if (kc != k0) __syncthreads();             // prev chunk's compute done
#pragma unroll
        for (int r = 0; r < 8; ++r) {
            const int idx = r * 256 + t;
            const int nn  = idx >> 5;
            const int kk4 = idx & 31;
            xs[kk4 * 64 + (nn ^ kk4)] = g[r];      // conflict-free write
        }
        __syncthreads();

        const float* wc = wr + kc;
#pragma unroll 2
        for (int k4 = 0; k4 < 32; ++k4) {
            const float4 xv = xs[k4 * 64 + (lane ^ k4)];   // conflict-free read
            const v2f xa = {xv.x, xv.y};
            const v2f xb = {xv.z, xv.w};
#pragma unroll
            for (int jj = 0; jj < 4; ++jj) {
                const float4 wv = *(const float4*)(wc + (size_t)jj * K_ + k4 * 4); // s_load
                const v2f wa = {wv.x, wv.y};
                const v2f wb = {wv.z, wv.w};
                const v2f pA = xa * wa;            // v_pk_mul_f32
                const v2f pB = xb * wb;
                mx[jj] = fmaxf(fmaxf(mx[jj], pA.x), pA.y);   // v_max3_f32
                mn[jj] = fminf(fminf(mn[jj], pA.x), pA.y);
                mx[jj] = fmaxf(fmaxf(mx[jj], pB.x), pB.y);
                mn[jj] = fminf(fminf(mn[jj], pB.x), pB.y);
            }
        }
    }

    if (ksplit == 1) {
        const float4 bi = *(const float4*)(bias + j0);
        float4 o;
        o.x = mx[0] + mn[0] + bi.x;
        o.y = mx[1] + mn[1] + bi.y;
        o.z = mx[2] + mn[2] + bi.z;
        o.w = mx[3] + mn[3] + bi.w;
        *(float4*)(out + (size_t)(n0 + lane) * J_ + j0) = o;
    } else {
        const size_t off = ((size_t)blockIdx.z * N_ + n0 + lane) * J_ + j0;
        *(float4*)(pmax + off) = make_float4(mx[0], mx[1], mx[2], mx[3]);
        *(float4*)(pmin + off) = make_float4(mn[0], mn[1], mn[2], mn[3]);
    }
}

// Fold the 2 K-splits, add bias. Fully coalesced.
__global__ __launch_bounds__(256) void mam_combine(
    const float* __restrict__ pmax, const float* __restrict__ pmin,
    const float* __restrict__ bias, float* __restrict__ out)
{
    const int f = blockIdx.x * 256 + threadIdx.x;   // float4 index, 131072 total
    const int PLANE4 = N_ * J_ / 4;
    const float4* pm = (const float4*)pmax;
    const float4* pn = (const float4*)pmin;
    const float4 a0 = pm[f], a1 = pm[PLANE4 + f];
    const float4 b0 = pn[f], b1 = pn[PLANE4 + f];
    const float4 bi = ((const float4*)bias)[f & (J_ / 4 - 1)];
    float4 o;
    o.x = fmaxf(a0.x, a1.x) + fminf(b0.x, b1.x) + bi.x;
    o.y = fmaxf(a0.y, a1.y) + fminf(b0.y, b1.y) + bi.y;
    o.z = fmaxf(a0.z, a1.z) + fminf(b0.z, b1.z) + bi.z;
    o.w = fmaxf(a0.w, a1.w) + fminf(b0.w, b1.w) + bi.w;
    ((float4*)out)[f] = o;
}

extern "C" void kernel_launch(void* const* d_in, const int* in_sizes, int n_in,
                              void* d_out, int out_size, void* d_ws, size_t ws_size,
                              hipStream_t stream) {
    const float* x    = (const float*)d_in[0];
    const float* w    = (const float*)d_in[1];
    const float* bias = (const float*)d_in[2];
    float* out = (float*)d_out;

    const size_t need = (size_t)2 * 2 * N_ * J_ * sizeof(float);  // 8 MB
    if (ws_size >= need) {
        float* pmax = (float*)d_ws;
        float* pmin = pmax + (size_t)2 * N_ * J_;
        dim3 grid(N_ / 64, J_ / 16, 2);            // 32 x 16 x 2 = 1024 blocks
        mam_main<<<grid, 256, 0, stream>>>(x, w, bias, out, pmax, pmin, 2);
        mam_combine<<<(N_ * J_ / 4) / 256, 256, 0, stream>>>(pmax, pmin, bias, out);
    } else {
        dim3 grid(N_ / 64, J_ / 16, 1);            // 512 blocks, direct out
        mam_main<<<grid, 256, 0, stream>>>(x, w, bias, out, nullptr, nullptr, 1);
    }
}

// Round 5
// 84.571 us; speedup vs baseline: 1.1783x; 1.1733x over previous
//
#include <hip/hip_runtime.h>
#include <math.h>

#define N_ 2048
#define K_ 512
#define J_ 256
#define SPLIT 8
#define KR  (K_ / SPLIT)   // 64 k per block
#define KR4 (KR / 4)       // 16 float4 k-steps

typedef __attribute__((ext_vector_type(2))) float v2f;

// Block: 64n x 64j x 64k. 256 threads, thread-tile 4n x 4j, k-vec 4.
// Both x and w staged in LDS (NO s_load in the loop — R4's 0.5% VALUBusy lesson).
// LDS col-swizzle c = (k4 + row/4) & 15: staging writes 2-way, x-reads 4 addrs on
// 4 bank-groups (16-lane broadcast), w-reads 16 addrs 2-way (4-lane broadcast) — all free.
// 1024 blocks -> 4 blocks/CU -> 4 waves/SIMD; single barrier.
__global__ __launch_bounds__(256, 4) void mam_partial(
    const float* __restrict__ x, const float* __restrict__ w,
    float* __restrict__ pmax, float* __restrict__ pmin)
{
    __shared__ __align__(16) float xs[64 * 64];   // 16 KB
    __shared__ __align__(16) float wsh[64 * 64];  // 16 KB

    const int t  = threadIdx.x;
    const int tx = t & 15;          // j group (4 cols)
    const int ty = t >> 4;          // n group (4 rows)
    const int n0 = blockIdx.x * 64;
    const int j0 = blockIdx.y * 64;
    const int kc = blockIdx.z * KR;

    // ---- stage x and w tiles: 64 rows x 16 float4 each, 4 float4/thread/tile ----
#pragma unroll
    for (int r = 0; r < 4; ++r) {
        const int idx = r * 256 + t;
        const int row = idx >> 4;           // 0..63
        const int kq  = idx & 15;
        const int c   = (kq + (row >> 2)) & 15;    // swizzled column
        const float4 gx = *(const float4*)(x + (size_t)(n0 + row) * K_ + kc + kq * 4);
        *(float4*)&xs[row * 64 + c * 4] = gx;
        const float4 gw = *(const float4*)(w + (size_t)(j0 + row) * K_ + kc + kq * 4);
        *(float4*)&wsh[row * 64 + c * 4] = gw;
    }
    __syncthreads();   // the only barrier

    float mx[4][4], mn[4][4];
#pragma unroll
    for (int i = 0; i < 4; ++i)
#pragma unroll
        for (int j = 0; j < 4; ++j) { mx[i][j] = -__builtin_inff(); mn[i][j] = __builtin_inff(); }

#pragma unroll 4
    for (int k4 = 0; k4 < KR4; ++k4) {
        float4 xv[4], wv[4];
#pragma unroll
        for (int i = 0; i < 4; ++i)          // n = ty*4+i, (n>>2)==ty
            xv[i] = *(const float4*)&xs[(ty * 4 + i) * 64 + (((k4 + ty) & 15) * 4)];
#pragma unroll
        for (int j = 0; j < 4; ++j)          // j = tx*4+j, (j>>2)==tx
            wv[j] = *(const float4*)&wsh[(tx * 4 + j) * 64 + (((k4 + tx) & 15) * 4)];
#pragma unroll
        for (int i = 0; i < 4; ++i) {
            const v2f xa = {xv[i].x, xv[i].y};
            const v2f xb = {xv[i].z, xv[i].w};
#pragma unroll
            for (int j = 0; j < 4; ++j) {
                const v2f wa = {wv[j].x, wv[j].y};
                const v2f wb = {wv[j].z, wv[j].w};
                const v2f pA = xa * wa;       // v_pk_mul_f32
                const v2f pB = xb * wb;
                mx[i][j] = fmaxf(fmaxf(mx[i][j], pA.x), pA.y);   // v_max3_f32
                mn[i][j] = fminf(fminf(mn[i][j], pA.x), pA.y);
                mx[i][j] = fmaxf(fmaxf(mx[i][j], pB.x), pB.y);
                mn[i][j] = fminf(fminf(mn[i][j], pB.x), pB.y);
            }
        }
    }

    // ---- store partials [split][n][j], lanes tx-consecutive -> coalesced ----
    const size_t base = ((size_t)blockIdx.z * N_ + n0 + ty * 4) * J_ + j0 + tx * 4;
#pragma unroll
    for (int i = 0; i < 4; ++i) {
        *(float4*)(pmax + base + (size_t)i * J_) = make_float4(mx[i][0], mx[i][1], mx[i][2], mx[i][3]);
        *(float4*)(pmin + base + (size_t)i * J_) = make_float4(mn[i][0], mn[i][1], mn[i][2], mn[i][3]);
    }
}

// Fold 8 K-splits + bias. 512 blocks x 256 thr, one float4 out per thread.
__global__ __launch_bounds__(256) void mam_combine(
    const float* __restrict__ pmax, const float* __restrict__ pmin,
    const float* __restrict__ bias, float* __restrict__ out)
{
    const int f = blockIdx.x * 256 + threadIdx.x;   // 131072 float4
    const int PLANE4 = N_ * J_ / 4;
    const float4* pm = (const float4*)pmax;
    const float4* pn = (const float4*)pmin;

    float4 a = pm[f];
    float4 b = pn[f];
#pragma unroll
    for (int s = 1; s < SPLIT; ++s) {
        const float4 a2 = pm[(size_t)s * PLANE4 + f];
        const float4 b2 = pn[(size_t)s * PLANE4 + f];
        a.x = fmaxf(a.x, a2.x); a.y = fmaxf(a.y, a2.y);
        a.z = fmaxf(a.z, a2.z); a.w = fmaxf(a.w, a2.w);
        b.x = fminf(b.x, b2.x); b.y = fminf(b.y, b2.y);
        b.z = fminf(b.z, b2.z); b.w = fminf(b.w, b2.w);
    }
    const float4 bi = ((const float4*)bias)[f & (J_ / 4 - 1)];
    float4 o;
    o.x = a.x + b.x + bi.x;
    o.y = a.y + b.y + bi.y;
    o.z = a.z + b.z + bi.z;
    o.w = a.w + b.w + bi.w;
    ((float4*)out)[f] = o;
}

// Fallback if ws is too small (not expected: ws ~256 MB per profile).
__global__ __launch_bounds__(256) void mam_naive(
    const float* __restrict__ x, const float* __restrict__ w,
    const float* __restrict__ bias, float* __restrict__ out)
{
    const int n = blockIdx.x;
    const int j = threadIdx.x;
    float mx = -__builtin_inff(), mn = __builtin_inff();
    for (int k = 0; k < K_; ++k) {
        const float p = x[(size_t)n * K_ + k] * w[(size_t)j * K_ + k];
        mx = fmaxf(mx, p);
        mn = fminf(mn, p);
    }
    out[(size_t)n * J_ + j] = mx + mn + bias[j];
}

extern "C" void kernel_launch(void* const* d_in, const int* in_sizes, int n_in,
                              void* d_out, int out_size, void* d_ws, size_t ws_size,
                              hipStream_t stream) {
    const float* x    = (const float*)d_in[0];
    const float* w    = (const float*)d_in[1];
    const float* bias = (const float*)d_in[2];
    float* out = (float*)d_out;

    const size_t need = (size_t)SPLIT * 2 * N_ * J_ * sizeof(float);  // 32 MB
    if (ws_size >= need) {
        float* pmax = (float*)d_ws;
        float* pmin = pmax + (size_t)SPLIT * N_ * J_;
        dim3 grid(N_ / 64, J_ / 64, SPLIT);        // 32 x 4 x 8 = 1024 blocks
        mam_partial<<<grid, 256, 0, stream>>>(x, w, pmax, pmin);
        mam_combine<<<(N_ * J_ / 4) / 256, 256, 0, stream>>>(pmax, pmin, bias, out);
    } else {
        mam_naive<<<N_, 256, 0, stream>>>(x, w, bias, out);
    }
}